// Round 9
// baseline (277.236 us; speedup 1.0000x reference)
//
#include <hip/hip_runtime.h>
#include <stdint.h>

#define LL 1024
#define NB 8
#define EE 1024
#define HH 16
#define DD 64
#define MM (LL*NB)      // 8192 rows (l*NB+n)
#define K3 (3*EE)       // 3072

typedef __attribute__((ext_vector_type(8))) short bf16x8;   // 8 bf16 in 4 VGPRs
typedef __attribute__((ext_vector_type(4))) float f32x4;
typedef __attribute__((ext_vector_type(4))) unsigned short u16x4;
typedef __attribute__((ext_vector_type(8))) unsigned short u16x8;

__device__ __forceinline__ unsigned short f2bf(float f) {
  uint32_t u = __builtin_bit_cast(uint32_t, f);
  u += 0x7fffu + ((u >> 16) & 1u);           // RNE
  return (unsigned short)(u >> 16);
}
// HW RNE pack: dst = [bf16(hi)|bf16(lo)] — bit-identical to f2bf pairs
__device__ __forceinline__ uint32_t cvtpk(float lo, float hi) {
  uint32_t d;
  asm volatile("v_cvt_pk_bf16_f32 %0, %1, %2" : "=v"(d) : "v"(lo), "v"(hi));
  return d;
}
__device__ __forceinline__ f32x4 mfma16(bf16x8 a, bf16x8 b, f32x4 c) {
  return __builtin_amdgcn_mfma_f32_16x16x32_bf16(a, b, c, 0, 0, 0);
}
__device__ __forceinline__ void gload16(const unsigned short* src, unsigned short* dst) {
  __builtin_amdgcn_global_load_lds(
      (const __attribute__((address_space(1))) uint32_t*)src,
      (__attribute__((address_space(3))) uint32_t*)dst, 16, 0, 0);
}

// ---------------- fp32 -> bf16 convert ----------------
__global__ void cvt_kernel(const float* __restrict__ src, unsigned short* __restrict__ dst, int n4) {
  for (int i = blockIdx.x * blockDim.x + threadIdx.x; i < n4; i += gridDim.x * blockDim.x) {
    f32x4 v = ((const f32x4*)src)[i];
    u16x4 o;
    o[0] = f2bf(v[0]); o[1] = f2bf(v[1]); o[2] = f2bf(v[2]); o[3] = f2bf(v[3]);
    ((u16x4*)dst)[i] = o;
  }
}

// ---------------- GEMM: C[m][c] = sum_k A[m][k]*B[c][k] + bias[c] ----------------
// Double-buffered LDS tiles (32 KB), stage issued right after the single
// per-K-step barrier. MODE 0: fp32 out C[m][1024].  MODE 1 (NN=3072): bf16 out
// via LDS-coalesced epilogue, routed per column region:
//   c in [0,1024)    -> qo[m][c] * 0.125 (exact)
//   c in [1024,2048) -> kto[n][h][l][d]
//   c in [2048,3072) -> vo[m][c-2048]
template<int MODE>
__global__ __launch_bounds__(256) void gemm_bt(
    const unsigned short* __restrict__ A, const unsigned short* __restrict__ B,
    const float* __restrict__ bias, float* __restrict__ Cf,
    unsigned short* __restrict__ qo, unsigned short* __restrict__ kto,
    unsigned short* __restrict__ vo)
{
  constexpr int NNc = (MODE == 1) ? 3072 : 1024;
  constexpr int BPX = NNc / 1024;            // bcols per XCD
  constexpr int KD  = 1024;

  __shared__ __align__(16) unsigned short smem[16384];   // 32 KB: a0|b0|a1|b1

  const int bid = blockIdx.x;
  const int xcd = bid & 7;
  const int t = bid >> 3;
  const int brow = t / BPX;
  const int bcol = xcd * BPX + t % BPX;

  const int tid = threadIdx.x;
  const int w = tid >> 6, lane = tid & 63;
  const int wr = w >> 1, wc = w & 1;
  const int lrow = lane & 15, g = lane >> 4;

  f32x4 acc[4][4];
#pragma unroll
  for (int i = 0; i < 4; ++i)
#pragma unroll
    for (int j = 0; j < 4; ++j) acc[i][j] = (f32x4){0.f, 0.f, 0.f, 0.f};

  const int r_in = lane >> 2;
  const int u = lane & 3;

  auto stage = [&](int kt) {
    unsigned short* a_lds = smem + ((kt & 1) ? 8192 : 0);
    unsigned short* b_lds = a_lds + 4096;
    const size_t kcol = (size_t)kt * 32 + u * 8;
    gload16(A + (size_t)(brow * 128 + 16 * w + r_in) * KD + kcol,       &a_lds[(16 * w) * 32]);
    gload16(A + (size_t)(brow * 128 + 16 * (w + 4) + r_in) * KD + kcol, &a_lds[(16 * (w + 4)) * 32]);
    gload16(B + (size_t)(bcol * 128 + 16 * w + r_in) * KD + kcol,       &b_lds[(16 * w) * 32]);
    gload16(B + (size_t)(bcol * 128 + 16 * (w + 4) + r_in) * KD + kcol, &b_lds[(16 * (w + 4)) * 32]);
  };

  const int KT = KD >> 5;
  stage(0);
  for (int kt = 0; kt < KT; ++kt) {
    __syncthreads();                         // buf[kt&1] staged; prev reads joined
    if (kt + 1 < KT) stage(kt + 1);          // early prefetch into buf^1
    const unsigned short* a_lds = smem + ((kt & 1) ? 8192 : 0);
    const unsigned short* b_lds = a_lds + 4096;
    bf16x8 af[4], bfr[4];
#pragma unroll
    for (int mt = 0; mt < 4; ++mt)
      af[mt] = *(const bf16x8*)&a_lds[(wr * 64 + mt * 16 + lrow) * 32 + g * 8];
#pragma unroll
    for (int nt = 0; nt < 4; ++nt)
      bfr[nt] = *(const bf16x8*)&b_lds[(wc * 64 + nt * 16 + lrow) * 32 + g * 8];
#pragma unroll
    for (int mt = 0; mt < 4; ++mt)
#pragma unroll
      for (int nt = 0; nt < 4; ++nt)
        acc[mt][nt] = mfma16(af[mt], bfr[nt], acc[mt][nt]);
  }

  if (MODE == 0) {
#pragma unroll
    for (int nt = 0; nt < 4; ++nt) {
      const int c = bcol * 128 + wc * 64 + nt * 16 + lrow;
      const float bv = bias[c];
#pragma unroll
      for (int mt = 0; mt < 4; ++mt) {
        const int m0 = brow * 128 + wr * 64 + mt * 16 + g * 4;
#pragma unroll
        for (int j = 0; j < 4; ++j)
          Cf[(size_t)(m0 + j) * NNc + c] = acc[mt][nt][j] + bv;
      }
    }
  } else {
    __syncthreads();                         // all tile reads done before reuse
    const float qs = (bcol < 8) ? 0.125f : 1.0f;
#pragma unroll
    for (int nt = 0; nt < 4; ++nt) {
      const int c = bcol * 128 + wc * 64 + nt * 16 + lrow;
      const float bv = bias[c];
      const int lc = wc * 64 + nt * 16 + lrow;
#pragma unroll
      for (int mt = 0; mt < 4; ++mt) {
        const int lr0 = wr * 64 + mt * 16 + g * 4;
#pragma unroll
        for (int j = 0; j < 4; ++j)
          smem[(lr0 + j) * 128 + lc] = f2bf((acc[mt][nt][j] + bv) * qs);
      }
    }
    __syncthreads();
#pragma unroll
    for (int i = 0; i < 8; ++i) {
      const int unit = i * 256 + tid;        // 0..2047
      const int r = unit >> 4, cu = unit & 15;
      const u16x8 val = *(const u16x8*)&smem[r * 128 + cu * 8];
      const int m = brow * 128 + r;
      const int c = bcol * 128 + cu * 8;
      const int region = c >> 10, cl = c & 1023;
      if (region == 0)      *(u16x8*)&qo[(size_t)m * EE + cl] = val;
      else if (region == 2) *(u16x8*)&vo[(size_t)m * EE + cl] = val;
      else *(u16x8*)&kto[((size_t)((m & 7) * HH + (cl >> 6)) * LL + (m >> 3)) * DD + (cl & 63)] = val;
    }
  }
}

// ---------------- V transpose: v[m][1024] -> vt[n][h][d][s] ----------------
__global__ void transpose_v(const unsigned short* __restrict__ v, unsigned short* __restrict__ vt) {
  __shared__ __align__(16) unsigned short tile[64][68];
  const int b = blockIdx.x;                 // 2048
  const int lchunk = b & 15, h = (b >> 4) & 15, n = b >> 8;
  const int t = threadIdx.x;
  const int c4 = (t & 15) * 4, r = t >> 4;
#pragma unroll
  for (int p = 0; p < 4; ++p) {
    const int l = lchunk * 64 + p * 16 + r;
    u16x4 x = *(const u16x4*)&v[(size_t)(l * NB + n) * EE + h * DD + c4];
    *(u16x4*)&tile[p * 16 + r][c4] = x;
  }
  __syncthreads();
#pragma unroll
  for (int p = 0; p < 4; ++p) {
    const int d = p * 16 + r;
    u16x4 o;
#pragma unroll
    for (int i = 0; i < 4; ++i) o[i] = tile[c4 + i][d];
    *(u16x4*)&vt[((size_t)(n * HH + h) * DD + d) * LL + lchunk * 64 + c4] = o;
  }
}

// ---------------- flash attention (single pass, unnormalized accum) ----------------
// grid 1024 = n(8, XCD) x h(16) x ltile(8 of 128 rows); block 256 = 4 waves.
// BARRIER-FREE: K and V fragments read directly from global (L2-resident slabs);
// waves fully decoupled, each free-runs its own pipeline. Two q-tiles per wave
// for ILP; per-wave padded P LDS (in-order DS per wave => correct, no fences).
// #pragma unroll 2 exposes two chunks' independent chains to the scheduler.
__global__ __launch_bounds__(256) void attn_flash(
    const unsigned short* __restrict__ q,    // [m][1024] bf16, pre-scaled by 0.125
    const unsigned short* __restrict__ kt,   // [n][h][s][64]
    const unsigned short* __restrict__ vt,   // [n][h][64][1024]
    unsigned short* __restrict__ ctxo,       // [m][1024] bf16
    float* __restrict__ rinvb)               // [n][h][1024]
{
  __shared__ __align__(16) unsigned short pl[4][2][16][72];   // [wave][tile][l][s]

  const int bid = blockIdx.x;
  const int n = bid & 7;
  const int rest = bid >> 3;        // 0..127
  const int h = rest >> 3;          // 0..15
  const int lt = (rest & 7) << 7;   // 0..896 step 128
  const int tid = threadIdx.x;
  const int wv = tid >> 6, lane = tid & 63;
  const int ll = lane & 15, g = lane >> 4;

  const int ltA = lt + wv * 16 + ll;
  const int ltB = lt + 64 + wv * 16 + ll;
  const unsigned short* qpA = q + ((size_t)ltA * NB + n) * EE + h * DD + g * 8;
  const unsigned short* qpB = q + ((size_t)ltB * NB + n) * EE + h * DD + g * 8;
  const bf16x8 qfA0 = *(const bf16x8*)qpA;
  const bf16x8 qfA1 = *(const bf16x8*)(qpA + 32);
  const bf16x8 qfB0 = *(const bf16x8*)qpB;
  const bf16x8 qfB1 = *(const bf16x8*)(qpB + 32);

  const unsigned short* kbase = kt + (size_t)(n * HH + h) * LL * DD + (size_t)ll * DD + g * 8;
  const unsigned short* vbase = vt + (size_t)(n * HH + h) * DD * LL;

  f32x4 ctxA[4], ctxB[4];
#pragma unroll
  for (int i = 0; i < 4; ++i) { ctxA[i] = (f32x4){0.f,0.f,0.f,0.f}; ctxB[i] = (f32x4){0.f,0.f,0.f,0.f}; }
  f32x4 sumA = (f32x4){0.f,0.f,0.f,0.f}, sumB = (f32x4){0.f,0.f,0.f,0.f};

  char* plbA = (char*)&pl[wv][0][0][0];
  char* plbB = (char*)&pl[wv][1][0][0];

#pragma unroll 2
  for (int ch = 0; ch < 16; ++ch) {
    // V fragments for this chunk (consumed at PV; latency covered by QK+exp)
    bf16x8 vf0[4], vf1[4];
#pragma unroll
    for (int dt = 0; dt < 4; ++dt) {
      const unsigned short* vp = vbase + (size_t)(dt * 16 + ll) * LL + ch * 64 + g * 8;
      vf0[dt] = *(const bf16x8*)vp;
      vf1[dt] = *(const bf16x8*)(vp + 32);
    }

    // QK^T (swapped: lane ll owns q-row ll) + exp + stage P, K direct from L2
#pragma unroll
    for (int t = 0; t < 4; ++t) {
      const unsigned short* kp = kbase + (size_t)(ch * 64 + t * 16) * DD;
      bf16x8 kf0 = *(const bf16x8*)kp;
      bf16x8 kf1 = *(const bf16x8*)(kp + 32);
      f32x4 scA = (f32x4){0.f,0.f,0.f,0.f};
      f32x4 scB = (f32x4){0.f,0.f,0.f,0.f};
      scA = mfma16(kf0, qfA0, scA); scA = mfma16(kf1, qfA1, scA);
      scB = mfma16(kf0, qfB0, scB); scB = mfma16(kf1, qfB1, scB);
      f32x4 pA, pB;
#pragma unroll
      for (int j = 0; j < 4; ++j) { pA[j] = __expf(scA[j]); pB[j] = __expf(scB[j]); }
      sumA += pA; sumB += pB;
      uint2 wA; wA.x = cvtpk(pA[0], pA[1]); wA.y = cvtpk(pA[2], pA[3]);
      uint2 wB; wB.x = cvtpk(pB[0], pB[1]); wB.y = cvtpk(pB[2], pB[3]);
      *(uint2*)(plbA + ll * 144 + (t * 16 + g * 4) * 2) = wA;
      *(uint2*)(plbB + ll * 144 + (t * 16 + g * 4) * 2) = wB;
    }
    const bf16x8 pfA0 = *(const bf16x8*)(plbA + ll * 144 + g * 16);
    const bf16x8 pfA1 = *(const bf16x8*)(plbA + ll * 144 + 64 + g * 16);
    const bf16x8 pfB0 = *(const bf16x8*)(plbB + ll * 144 + g * 16);
    const bf16x8 pfB1 = *(const bf16x8*)(plbB + ll * 144 + 64 + g * 16);
#pragma unroll
    for (int dt = 0; dt < 4; ++dt) {
      ctxA[dt] = mfma16(vf0[dt], pfA0, ctxA[dt]);
      ctxA[dt] = mfma16(vf1[dt], pfA1, ctxA[dt]);
      ctxB[dt] = mfma16(vf0[dt], pfB0, ctxB[dt]);
      ctxB[dt] = mfma16(vf1[dt], pfB1, ctxB[dt]);
    }
  }

  float sA = sumA[0] + sumA[1] + sumA[2] + sumA[3];
  sA += __shfl_xor(sA, 16); sA += __shfl_xor(sA, 32);
  float sB = sumB[0] + sumB[1] + sumB[2] + sumB[3];
  sB += __shfl_xor(sB, 16); sB += __shfl_xor(sB, 32);
  const float rinvA = 1.0f / sA, rinvB = 1.0f / sB;
  if (lane < 16) {
    rinvb[(size_t)(n * HH + h) * LL + lt + wv * 16 + lane] = rinvA;
    rinvb[(size_t)(n * HH + h) * LL + lt + 64 + wv * 16 + lane] = rinvB;
  }

  unsigned short* cpA = ctxo + ((size_t)ltA * NB + n) * EE + h * DD;
  unsigned short* cpB = ctxo + ((size_t)ltB * NB + n) * EE + h * DD;
#pragma unroll
  for (int dt = 0; dt < 4; ++dt) {
    uint2 oA; oA.x = cvtpk(ctxA[dt][0]*rinvA, ctxA[dt][1]*rinvA);
    oA.y = cvtpk(ctxA[dt][2]*rinvA, ctxA[dt][3]*rinvA);
    uint2 oB; oB.x = cvtpk(ctxB[dt][0]*rinvB, ctxB[dt][1]*rinvB);
    oB.y = cvtpk(ctxB[dt][2]*rinvB, ctxB[dt][3]*rinvB);
    *(uint2*)(cpA + dt * 16 + g * 4) = oA;
    *(uint2*)(cpB + dt * 16 + g * 4) = oB;
  }
}

// ---------------- head-mean attention output (recompute QK with known rinv) ----------------
// grid 1024 = n(8, XCD) x [sh(8 of 128 s) x lt(16 of 64 rows)]; block 256 = 4 waves.
// Next-head K stage issued right after the barrier (after q loads).
__global__ __launch_bounds__(256) void attn_mean(
    const unsigned short* __restrict__ q,    // [m][1024] bf16, pre-scaled by 0.125
    const unsigned short* __restrict__ kt,   // [n][h][s][64]
    const float* __restrict__ rinvb,         // [n][h][1024]
    float* __restrict__ attn_out)            // [n][1024][1024]
{
  __shared__ __align__(16) unsigned short kc[2][128][64];  // 32KB, swizzled

  const int bid = blockIdx.x;
  const int n = bid & 7;
  const int r = bid >> 3;                    // 0..127
  const int sh = r & 7;
  const int lt = (r >> 3) << 6;
  const int tid = threadIdx.x;
  const int wv = tid >> 6, lane = tid & 63;
  const int ll = lane & 15, g = lane >> 4;
  const int a3 = ll & 7;
  const int sb = sh << 7;
  const int lrow = lt + wv * 16 + ll;

  const int r8 = lane >> 3;
  const int c16 = (lane & 7) ^ r8;
  const int kof0 = ll * 128 + ((g ^ a3) << 4);
  const int kof1 = ll * 128 + (((4 + g) ^ a3) << 4);

  const unsigned short* kwin = kt + (size_t)n * HH * LL * DD + (size_t)sb * DD;

  auto stage = [&](int buf, int h) {
    unsigned short* kd = &kc[buf][wv * 32][0];
    const unsigned short* src = kwin + (size_t)h * LL * DD + (size_t)(wv * 32) * DD;
#pragma unroll
    for (int i = 0; i < 4; ++i)
      gload16(src + (size_t)(i * 8 + r8) * DD + c16 * 8, kd + i * 8 * 64);
  };

  float rv[16];
#pragma unroll
  for (int h = 0; h < HH; ++h) rv[h] = rinvb[(size_t)(n * HH + h) * LL + lrow];

  const unsigned short* qb2 = q + ((size_t)lrow * NB + n) * EE + g * 8;

  f32x4 acc[8];
#pragma unroll
  for (int i = 0; i < 8; ++i) acc[i] = (f32x4){0.f, 0.f, 0.f, 0.f};

  stage(0, 0);
  for (int h = 0; h < HH; ++h) {
    __syncthreads();                 // buf[h&1] staged; prev reads joined
    const char* kb = (const char*)&kc[h & 1][0][0];
    const unsigned short* qp = qb2 + h * DD;
    const bf16x8 qf0 = *(const bf16x8*)qp;   // q loads first (consumed this iter)
    const bf16x8 qf1 = *(const bf16x8*)(qp + 32);
    if (h + 1 < HH) stage((h + 1) & 1, h + 1);   // early prefetch
    const float rvh = rv[h];
#pragma unroll
    for (int t = 0; t < 8; ++t) {
      bf16x8 kf0 = *(const bf16x8*)(kb + t * 2048 + kof0);
      bf16x8 kf1 = *(const bf16x8*)(kb + t * 2048 + kof1);
      f32x4 sc = (f32x4){0.f, 0.f, 0.f, 0.f};
      sc = mfma16(kf0, qf0, sc);
      sc = mfma16(kf1, qf1, sc);
#pragma unroll
      for (int j = 0; j < 4; ++j) acc[t][j] += __expf(sc[j]) * rvh;
    }
  }

  float* ap = attn_out + ((size_t)n * LL + lrow) * LL + sb + g * 4;
#pragma unroll
  for (int t = 0; t < 8; ++t) *(f32x4*)(ap + t * 16) = acc[t] * 0.0625f;
}

extern "C" void kernel_launch(void* const* d_in, const int* in_sizes, int n_in,
                              void* d_out, int out_size, void* d_ws, size_t ws_size,
                              hipStream_t stream) {
  const float* x   = (const float*)d_in[0];
  const float* win = (const float*)d_in[1];
  const float* bin = (const float*)d_in[2];
  const float* ow  = (const float*)d_in[3];
  const float* ob  = (const float*)d_in[4];
  float* out = (float*)d_out;

  const size_t need = ((size_t)MM * EE * 5 + (size_t)K3 * EE + (size_t)EE * EE) * 2
                    + (size_t)NB * HH * LL * 4;
  if (ws_size < need) return;

  unsigned short* ws  = (unsigned short*)d_ws;
  unsigned short* xb  = ws;                        // [8192][1024]  (reused as ctx)
  unsigned short* wb  = xb + (size_t)MM * EE;      // [3072][1024]
  unsigned short* owb = wb + (size_t)K3 * EE;      // [1024][1024]
  unsigned short* qb  = owb + (size_t)EE * EE;     // [8192][1024]
  unsigned short* ktb = qb + (size_t)MM * EE;      // [8][16][1024][64]
  unsigned short* vb  = ktb + (size_t)MM * EE;     // [8192][1024]
  unsigned short* vtb = vb + (size_t)MM * EE;      // [8][16][64][1024]
  float* rinvb = (float*)(vtb + (size_t)MM * EE);  // [8][16][1024]
  unsigned short* ctx = xb;

  cvt_kernel<<<2048, 256, 0, stream>>>(x, xb, (MM * EE) / 4);
  cvt_kernel<<<1024, 256, 0, stream>>>(win, wb, (K3 * EE) / 4);
  cvt_kernel<<<512, 256, 0, stream>>>(ow, owb, (EE * EE) / 4);
  gemm_bt<1><<<64 * (K3 / 128), 256, 0, stream>>>(xb, wb, bin, nullptr, qb, ktb, vb);
  transpose_v<<<2048, 256, 0, stream>>>(vb, vtb);
  attn_flash<<<1024, 256, 0, stream>>>(qb, ktb, vtb, ctx, rinvb);
  attn_mean<<<1024, 256, 0, stream>>>(qb, ktb, rinvb, out + (size_t)MM * EE);
  gemm_bt<0><<<64 * (EE / 128), 256, 0, stream>>>(ctx, owb, ob, out, nullptr, nullptr, nullptr);
}

// Round 10
// 207.603 us; speedup vs baseline: 1.3354x; 1.3354x over previous
//
#include <hip/hip_runtime.h>
#include <stdint.h>

#define LL 1024
#define NB 8
#define EE 1024
#define HH 16
#define DD 64
#define MM (LL*NB)      // 8192 rows (l*NB+n)
#define K3 (3*EE)       // 3072

typedef __attribute__((ext_vector_type(8))) short bf16x8;   // 8 bf16 in 4 VGPRs
typedef __attribute__((ext_vector_type(4))) float f32x4;
typedef __attribute__((ext_vector_type(4))) unsigned short u16x4;
typedef __attribute__((ext_vector_type(8))) unsigned short u16x8;

__device__ __forceinline__ unsigned short f2bf(float f) {
  uint32_t u = __builtin_bit_cast(uint32_t, f);
  u += 0x7fffu + ((u >> 16) & 1u);           // RNE
  return (unsigned short)(u >> 16);
}
// HW RNE pack: dst = [bf16(hi)|bf16(lo)] — bit-identical to f2bf pairs
__device__ __forceinline__ uint32_t cvtpk(float lo, float hi) {
  uint32_t d;
  asm volatile("v_cvt_pk_bf16_f32 %0, %1, %2" : "=v"(d) : "v"(lo), "v"(hi));
  return d;
}
__device__ __forceinline__ f32x4 mfma16(bf16x8 a, bf16x8 b, f32x4 c) {
  return __builtin_amdgcn_mfma_f32_16x16x32_bf16(a, b, c, 0, 0, 0);
}
__device__ __forceinline__ void gload16(const unsigned short* src, unsigned short* dst) {
  __builtin_amdgcn_global_load_lds(
      (const __attribute__((address_space(1))) uint32_t*)src,
      (__attribute__((address_space(3))) uint32_t*)dst, 16, 0, 0);
}

// ---------------- fp32 -> bf16 convert (all three inputs, one launch) ----------------
__global__ void cvt3_kernel(const float* __restrict__ a, const float* __restrict__ b,
                            const float* __restrict__ c,
                            unsigned short* __restrict__ da, unsigned short* __restrict__ db,
                            unsigned short* __restrict__ dc) {
  const int NA = (MM * EE) / 4, NBq = (K3 * EE) / 4, NC = (EE * EE) / 4;
  const int total = NA + NBq + NC;
  for (int i = blockIdx.x * blockDim.x + threadIdx.x; i < total; i += gridDim.x * blockDim.x) {
    const float* s; unsigned short* d; int j;
    if (i < NA)            { s = a; d = da; j = i; }
    else if (i < NA + NBq) { s = b; d = db; j = i - NA; }
    else                   { s = c; d = dc; j = i - NA - NBq; }
    f32x4 v = ((const f32x4*)s)[j];
    u16x4 o;
    o[0] = f2bf(v[0]); o[1] = f2bf(v[1]); o[2] = f2bf(v[2]); o[3] = f2bf(v[3]);
    ((u16x4*)d)[j] = o;
  }
}

// ---------------- GEMM: C[m][c] = sum_k A[m][k]*B[c][k] + bias[c] ----------------
// Double-buffered LDS tiles (32 KB), stage issued right after the single
// per-K-step barrier. MODE 0: fp32 out C[m][1024].  MODE 1 (NN=3072): bf16 out
// via LDS-coalesced epilogue, routed per column region:
//   c in [0,1024)    -> qo[m][c] * 0.125 (exact)
//   c in [1024,2048) -> kto[n][h][l][d]
//   c in [2048,3072) -> vo[m][c-2048]
template<int MODE>
__global__ __launch_bounds__(256) void gemm_bt(
    const unsigned short* __restrict__ A, const unsigned short* __restrict__ B,
    const float* __restrict__ bias, float* __restrict__ Cf,
    unsigned short* __restrict__ qo, unsigned short* __restrict__ kto,
    unsigned short* __restrict__ vo)
{
  constexpr int NNc = (MODE == 1) ? 3072 : 1024;
  constexpr int BPX = NNc / 1024;            // bcols per XCD
  constexpr int KD  = 1024;

  __shared__ __align__(16) unsigned short smem[16384];   // 32 KB: a0|b0|a1|b1

  const int bid = blockIdx.x;
  const int xcd = bid & 7;
  const int t = bid >> 3;
  const int brow = t / BPX;
  const int bcol = xcd * BPX + t % BPX;

  const int tid = threadIdx.x;
  const int w = tid >> 6, lane = tid & 63;
  const int wr = w >> 1, wc = w & 1;
  const int lrow = lane & 15, g = lane >> 4;

  f32x4 acc[4][4];
#pragma unroll
  for (int i = 0; i < 4; ++i)
#pragma unroll
    for (int j = 0; j < 4; ++j) acc[i][j] = (f32x4){0.f, 0.f, 0.f, 0.f};

  const int r_in = lane >> 2;
  const int u = lane & 3;

  auto stage = [&](int kt) {
    unsigned short* a_lds = smem + ((kt & 1) ? 8192 : 0);
    unsigned short* b_lds = a_lds + 4096;
    const size_t kcol = (size_t)kt * 32 + u * 8;
    gload16(A + (size_t)(brow * 128 + 16 * w + r_in) * KD + kcol,       &a_lds[(16 * w) * 32]);
    gload16(A + (size_t)(brow * 128 + 16 * (w + 4) + r_in) * KD + kcol, &a_lds[(16 * (w + 4)) * 32]);
    gload16(B + (size_t)(bcol * 128 + 16 * w + r_in) * KD + kcol,       &b_lds[(16 * w) * 32]);
    gload16(B + (size_t)(bcol * 128 + 16 * (w + 4) + r_in) * KD + kcol, &b_lds[(16 * (w + 4)) * 32]);
  };

  const int KT = KD >> 5;
  stage(0);
  for (int kt = 0; kt < KT; ++kt) {
    __syncthreads();                         // buf[kt&1] staged; prev reads joined
    if (kt + 1 < KT) stage(kt + 1);          // early prefetch into buf^1
    const unsigned short* a_lds = smem + ((kt & 1) ? 8192 : 0);
    const unsigned short* b_lds = a_lds + 4096;
    bf16x8 af[4], bfr[4];
#pragma unroll
    for (int mt = 0; mt < 4; ++mt)
      af[mt] = *(const bf16x8*)&a_lds[(wr * 64 + mt * 16 + lrow) * 32 + g * 8];
#pragma unroll
    for (int nt = 0; nt < 4; ++nt)
      bfr[nt] = *(const bf16x8*)&b_lds[(wc * 64 + nt * 16 + lrow) * 32 + g * 8];
#pragma unroll
    for (int mt = 0; mt < 4; ++mt)
#pragma unroll
      for (int nt = 0; nt < 4; ++nt)
        acc[mt][nt] = mfma16(af[mt], bfr[nt], acc[mt][nt]);
  }

  if (MODE == 0) {
#pragma unroll
    for (int nt = 0; nt < 4; ++nt) {
      const int c = bcol * 128 + wc * 64 + nt * 16 + lrow;
      const float bv = bias[c];
#pragma unroll
      for (int mt = 0; mt < 4; ++mt) {
        const int m0 = brow * 128 + wr * 64 + mt * 16 + g * 4;
#pragma unroll
        for (int j = 0; j < 4; ++j)
          Cf[(size_t)(m0 + j) * NNc + c] = acc[mt][nt][j] + bv;
      }
    }
  } else {
    __syncthreads();                         // all tile reads done before reuse
    const float qs = (bcol < 8) ? 0.125f : 1.0f;
#pragma unroll
    for (int nt = 0; nt < 4; ++nt) {
      const int c = bcol * 128 + wc * 64 + nt * 16 + lrow;
      const float bv = bias[c];
      const int lc = wc * 64 + nt * 16 + lrow;
#pragma unroll
      for (int mt = 0; mt < 4; ++mt) {
        const int lr0 = wr * 64 + mt * 16 + g * 4;
#pragma unroll
        for (int j = 0; j < 4; ++j)
          smem[(lr0 + j) * 128 + lc] = f2bf((acc[mt][nt][j] + bv) * qs);
      }
    }
    __syncthreads();
#pragma unroll
    for (int i = 0; i < 8; ++i) {
      const int unit = i * 256 + tid;        // 0..2047
      const int r = unit >> 4, cu = unit & 15;
      const u16x8 val = *(const u16x8*)&smem[r * 128 + cu * 8];
      const int m = brow * 128 + r;
      const int c = bcol * 128 + cu * 8;
      const int region = c >> 10, cl = c & 1023;
      if (region == 0)      *(u16x8*)&qo[(size_t)m * EE + cl] = val;
      else if (region == 2) *(u16x8*)&vo[(size_t)m * EE + cl] = val;
      else *(u16x8*)&kto[((size_t)((m & 7) * HH + (cl >> 6)) * LL + (m >> 3)) * DD + (cl & 63)] = val;
    }
  }
}

// ---------------- V transpose: v[m][1024] -> vt[n][h][d][s] ----------------
__global__ void transpose_v(const unsigned short* __restrict__ v, unsigned short* __restrict__ vt) {
  __shared__ __align__(16) unsigned short tile[64][68];
  const int b = blockIdx.x;                 // 2048
  const int lchunk = b & 15, h = (b >> 4) & 15, n = b >> 8;
  const int t = threadIdx.x;
  const int c4 = (t & 15) * 4, r = t >> 4;
#pragma unroll
  for (int p = 0; p < 4; ++p) {
    const int l = lchunk * 64 + p * 16 + r;
    u16x4 x = *(const u16x4*)&v[(size_t)(l * NB + n) * EE + h * DD + c4];
    *(u16x4*)&tile[p * 16 + r][c4] = x;
  }
  __syncthreads();
#pragma unroll
  for (int p = 0; p < 4; ++p) {
    const int d = p * 16 + r;
    u16x4 o;
#pragma unroll
    for (int i = 0; i < 4; ++i) o[i] = tile[c4 + i][d];
    *(u16x4*)&vt[((size_t)(n * HH + h) * DD + d) * LL + lchunk * 64 + c4] = o;
  }
}

// ---------------- flash attention (single pass, unnormalized accum) ----------------
// grid 512 = n(8, XCD) x h(16) x ltile(4 of 256 rows); block 256 = 4 waves.
// Each wave owns FOUR 16-row q-tiles: 4 independent QK->exp->PV chains hide
// latency; K ds_reads and V fragment loads amortized over 4 tiles. K chunk
// staged to LDS (XOR-swizzled source), double-buffered, 1 barrier/chunk.
__global__ __launch_bounds__(256) void attn_flash(
    const unsigned short* __restrict__ q,    // [m][1024] bf16, pre-scaled by 0.125
    const unsigned short* __restrict__ kt,   // [n][h][s][64]
    const unsigned short* __restrict__ vt,   // [n][h][64][1024]
    unsigned short* __restrict__ ctxo,       // [m][1024] bf16
    float* __restrict__ rinvb)               // [n][h][1024]
{
  __shared__ __align__(16) unsigned short kc[2][64][64];      // 16 KB, swizzled
  __shared__ __align__(16) unsigned short pl[4][4][16][72];   // 36.9 KB [wave][tile][l][s]

  const int bid = blockIdx.x;
  const int n = bid & 7;
  const int rest = bid >> 3;        // 0..63
  const int h = rest >> 2;          // 0..15
  const int lt = (rest & 3) << 8;   // 0, 256, 512, 768
  const int tid = threadIdx.x;
  const int wv = tid >> 6, lane = tid & 63;
  const int ll = lane & 15, g = lane >> 4;
  const int a3 = ll & 7;

  // q fragments for 4 tiles
  bf16x8 qf0[4], qf1[4];
#pragma unroll
  for (int T = 0; T < 4; ++T) {
    const int lr = lt + T * 64 + wv * 16 + ll;
    const unsigned short* qp = q + ((size_t)lr * NB + n) * EE + h * DD + g * 8;
    qf0[T] = *(const bf16x8*)qp;
    qf1[T] = *(const bf16x8*)(qp + 32);
  }

  const unsigned short* kslab = kt + (size_t)(n * HH + h) * LL * DD;
  const unsigned short* vbase = vt + (size_t)(n * HH + h) * DD * LL;

  // staging: lane lam -> LDS row lam/8, unit lam%8; source unit (lam%8)^(row&7)
  const int r8 = lane >> 3;
  const int c16 = (lane & 7) ^ r8;
  // swizzled read offsets (bytes; 128B rows): row&7 == ll&7 == a3
  const int kof0 = ll * 128 + ((g ^ a3) << 4);        // k units 0..3
  const int kof1 = ll * 128 + (((4 + g) ^ a3) << 4);  // k units 4..7

  auto stageK = [&](int buf, int ch) {
    unsigned short* kd = &kc[buf][wv * 16][0];
    const unsigned short* src = kslab + (size_t)(ch * 64 + wv * 16) * DD;
    gload16(src + (size_t)r8 * DD + c16 * 8,       kd);
    gload16(src + (size_t)(8 + r8) * DD + c16 * 8, kd + 8 * 64);
  };

  f32x4 ctx[4][4];    // [tile][dt] — static indices after full unroll
  f32x4 sum[4];
#pragma unroll
  for (int T = 0; T < 4; ++T) {
    sum[T] = (f32x4){0.f, 0.f, 0.f, 0.f};
#pragma unroll
    for (int dt = 0; dt < 4; ++dt) ctx[T][dt] = (f32x4){0.f, 0.f, 0.f, 0.f};
  }

  char* plb = (char*)&pl[wv][0][0][0];      // tile stride 2304 B, row stride 144 B

  stageK(0, 0);
  for (int ch = 0; ch < 16; ++ch) {
    __syncthreads();                 // buf[ch&1] staged; prev iter's reads joined
    const int buf = ch & 1;
    const char* kb = (const char*)&kc[buf][0][0];

    // V loads first (consumed at PV -> their waitcnt won't drain the stage)
    bf16x8 vf0[4], vf1[4];
#pragma unroll
    for (int dt = 0; dt < 4; ++dt) {
      const unsigned short* vp = vbase + (size_t)(dt * 16 + ll) * LL + ch * 64 + g * 8;
      vf0[dt] = *(const bf16x8*)vp;
      vf1[dt] = *(const bf16x8*)(vp + 32);
    }
    if (ch < 15) stageK(buf ^ 1, ch + 1);   // early prefetch, covered by chunk body

    // QK^T + exp + stage P, 4 tiles per K fragment
#pragma unroll
    for (int t = 0; t < 4; ++t) {
      const bf16x8 kf0 = *(const bf16x8*)(kb + t * 2048 + kof0);
      const bf16x8 kf1 = *(const bf16x8*)(kb + t * 2048 + kof1);
#pragma unroll
      for (int T = 0; T < 4; ++T) {
        f32x4 sc = (f32x4){0.f, 0.f, 0.f, 0.f};
        sc = mfma16(kf0, qf0[T], sc);
        sc = mfma16(kf1, qf1[T], sc);
        f32x4 p;
#pragma unroll
        for (int j = 0; j < 4; ++j) p[j] = __expf(sc[j]);
        sum[T] += p;
        uint2 wT; wT.x = cvtpk(p[0], p[1]); wT.y = cvtpk(p[2], p[3]);
        *(uint2*)(plb + T * 2304 + ll * 144 + (t * 16 + g * 4) * 2) = wT;
      }
    }
    // PV per tile (pf transient, caps register pressure)
#pragma unroll
    for (int T = 0; T < 4; ++T) {
      const bf16x8 pf0 = *(const bf16x8*)(plb + T * 2304 + ll * 144 + g * 16);
      const bf16x8 pf1 = *(const bf16x8*)(plb + T * 2304 + ll * 144 + 64 + g * 16);
#pragma unroll
      for (int dt = 0; dt < 4; ++dt) {
        ctx[T][dt] = mfma16(vf0[dt], pf0, ctx[T][dt]);
        ctx[T][dt] = mfma16(vf1[dt], pf1, ctx[T][dt]);
      }
    }
  }

  // per-tile row sums -> rinv, normalize, store
#pragma unroll
  for (int T = 0; T < 4; ++T) {
    float s1 = sum[T][0] + sum[T][1] + sum[T][2] + sum[T][3];
    s1 += __shfl_xor(s1, 16); s1 += __shfl_xor(s1, 32);
    const float rinv = 1.0f / s1;
    if (lane < 16) rinvb[(size_t)(n * HH + h) * LL + lt + T * 64 + wv * 16 + lane] = rinv;
    const int lr = lt + T * 64 + wv * 16 + ll;
    unsigned short* cp = ctxo + ((size_t)lr * NB + n) * EE + h * DD;
#pragma unroll
    for (int dt = 0; dt < 4; ++dt) {
      uint2 o;
      o.x = cvtpk(ctx[T][dt][0] * rinv, ctx[T][dt][1] * rinv);
      o.y = cvtpk(ctx[T][dt][2] * rinv, ctx[T][dt][3] * rinv);
      *(uint2*)(cp + dt * 16 + g * 4) = o;
    }
  }
}

// ---------------- head-mean attention output (recompute QK with known rinv) ----------------
// grid 1024 = n(8, XCD) x [sh(8 of 128 s) x lt(16 of 64 rows)]; block 256 = 4 waves.
// Next-head K stage issued right after the barrier (after q loads).
__global__ __launch_bounds__(256) void attn_mean(
    const unsigned short* __restrict__ q,    // [m][1024] bf16, pre-scaled by 0.125
    const unsigned short* __restrict__ kt,   // [n][h][s][64]
    const float* __restrict__ rinvb,         // [n][h][1024]
    float* __restrict__ attn_out)            // [n][1024][1024]
{
  __shared__ __align__(16) unsigned short kc[2][128][64];  // 32KB, swizzled

  const int bid = blockIdx.x;
  const int n = bid & 7;
  const int r = bid >> 3;                    // 0..127
  const int sh = r & 7;
  const int lt = (r >> 3) << 6;
  const int tid = threadIdx.x;
  const int wv = tid >> 6, lane = tid & 63;
  const int ll = lane & 15, g = lane >> 4;
  const int a3 = ll & 7;
  const int sb = sh << 7;
  const int lrow = lt + wv * 16 + ll;

  const int r8 = lane >> 3;
  const int c16 = (lane & 7) ^ r8;
  const int kof0 = ll * 128 + ((g ^ a3) << 4);
  const int kof1 = ll * 128 + (((4 + g) ^ a3) << 4);

  const unsigned short* kwin = kt + (size_t)n * HH * LL * DD + (size_t)sb * DD;

  auto stage = [&](int buf, int h) {
    unsigned short* kd = &kc[buf][wv * 32][0];
    const unsigned short* src = kwin + (size_t)h * LL * DD + (size_t)(wv * 32) * DD;
#pragma unroll
    for (int i = 0; i < 4; ++i)
      gload16(src + (size_t)(i * 8 + r8) * DD + c16 * 8, kd + i * 8 * 64);
  };

  float rv[16];
#pragma unroll
  for (int h = 0; h < HH; ++h) rv[h] = rinvb[(size_t)(n * HH + h) * LL + lrow];

  const unsigned short* qb2 = q + ((size_t)lrow * NB + n) * EE + g * 8;

  f32x4 acc[8];
#pragma unroll
  for (int i = 0; i < 8; ++i) acc[i] = (f32x4){0.f, 0.f, 0.f, 0.f};

  stage(0, 0);
  for (int h = 0; h < HH; ++h) {
    __syncthreads();                 // buf[h&1] staged; prev reads joined
    const char* kb = (const char*)&kc[h & 1][0][0];
    const unsigned short* qp = qb2 + h * DD;
    const bf16x8 qf0 = *(const bf16x8*)qp;   // q loads first (consumed this iter)
    const bf16x8 qf1 = *(const bf16x8*)(qp + 32);
    if (h + 1 < HH) stage((h + 1) & 1, h + 1);   // early prefetch
    const float rvh = rv[h];
#pragma unroll
    for (int t = 0; t < 8; ++t) {
      bf16x8 kf0 = *(const bf16x8*)(kb + t * 2048 + kof0);
      bf16x8 kf1 = *(const bf16x8*)(kb + t * 2048 + kof1);
      f32x4 sc = (f32x4){0.f, 0.f, 0.f, 0.f};
      sc = mfma16(kf0, qf0, sc);
      sc = mfma16(kf1, qf1, sc);
#pragma unroll
      for (int j = 0; j < 4; ++j) acc[t][j] += __expf(sc[j]) * rvh;
    }
  }

  float* ap = attn_out + ((size_t)n * LL + lrow) * LL + sb + g * 4;
#pragma unroll
  for (int t = 0; t < 8; ++t) *(f32x4*)(ap + t * 16) = acc[t] * 0.0625f;
}

extern "C" void kernel_launch(void* const* d_in, const int* in_sizes, int n_in,
                              void* d_out, int out_size, void* d_ws, size_t ws_size,
                              hipStream_t stream) {
  const float* x   = (const float*)d_in[0];
  const float* win = (const float*)d_in[1];
  const float* bin = (const float*)d_in[2];
  const float* ow  = (const float*)d_in[3];
  const float* ob  = (const float*)d_in[4];
  float* out = (float*)d_out;

  const size_t need = ((size_t)MM * EE * 5 + (size_t)K3 * EE + (size_t)EE * EE) * 2
                    + (size_t)NB * HH * LL * 4;
  if (ws_size < need) return;

  unsigned short* ws  = (unsigned short*)d_ws;
  unsigned short* xb  = ws;                        // [8192][1024]  (reused as ctx)
  unsigned short* wb  = xb + (size_t)MM * EE;      // [3072][1024]
  unsigned short* owb = wb + (size_t)K3 * EE;      // [1024][1024]
  unsigned short* qb  = owb + (size_t)EE * EE;     // [8192][1024]
  unsigned short* ktb = qb + (size_t)MM * EE;      // [8][16][1024][64]
  unsigned short* vb  = ktb + (size_t)MM * EE;     // [8192][1024]
  unsigned short* vtb = vb + (size_t)MM * EE;      // [8][16][64][1024]
  float* rinvb = (float*)(vtb + (size_t)MM * EE);  // [8][16][1024]
  unsigned short* ctx = xb;

  cvt3_kernel<<<2048, 256, 0, stream>>>(x, win, ow, xb, wb, owb);
  gemm_bt<1><<<64 * (K3 / 128), 256, 0, stream>>>(xb, wb, bin, nullptr, qb, ktb, vb);
  transpose_v<<<2048, 256, 0, stream>>>(vb, vtb);
  attn_flash<<<512, 256, 0, stream>>>(qb, ktb, vtb, ctx, rinvb);
  attn_mean<<<1024, 256, 0, stream>>>(qb, ktb, rinvb, out + (size_t)MM * EE);
  gemm_bt<0><<<64 * (EE / 128), 256, 0, stream>>>(ctx, owb, ob, out, nullptr, nullptr, nullptr);
}

// Round 11
// 203.553 us; speedup vs baseline: 1.3620x; 1.0199x over previous
//
#include <hip/hip_runtime.h>
#include <stdint.h>

#define LL 1024
#define NB 8
#define EE 1024
#define HH 16
#define DD 64
#define MM (LL*NB)      // 8192 rows (l*NB+n)
#define K3 (3*EE)       // 3072

typedef __attribute__((ext_vector_type(8))) short bf16x8;   // 8 bf16 in 4 VGPRs
typedef __attribute__((ext_vector_type(4))) float f32x4;
typedef __attribute__((ext_vector_type(4))) unsigned short u16x4;
typedef __attribute__((ext_vector_type(8))) unsigned short u16x8;

__device__ __forceinline__ unsigned short f2bf(float f) {
  uint32_t u = __builtin_bit_cast(uint32_t, f);
  u += 0x7fffu + ((u >> 16) & 1u);           // RNE
  return (unsigned short)(u >> 16);
}
// HW RNE pack: dst = [bf16(hi)|bf16(lo)] — bit-identical to f2bf pairs
__device__ __forceinline__ uint32_t cvtpk(float lo, float hi) {
  uint32_t d;
  asm volatile("v_cvt_pk_bf16_f32 %0, %1, %2" : "=v"(d) : "v"(lo), "v"(hi));
  return d;
}
__device__ __forceinline__ f32x4 mfma16(bf16x8 a, bf16x8 b, f32x4 c) {
  return __builtin_amdgcn_mfma_f32_16x16x32_bf16(a, b, c, 0, 0, 0);
}
__device__ __forceinline__ void gload16(const unsigned short* src, unsigned short* dst) {
  __builtin_amdgcn_global_load_lds(
      (const __attribute__((address_space(1))) uint32_t*)src,
      (__attribute__((address_space(3))) uint32_t*)dst, 16, 0, 0);
}

// ---------------- fp32 -> bf16 convert (all three inputs, one launch) ----------------
__global__ void cvt3_kernel(const float* __restrict__ a, const float* __restrict__ b,
                            const float* __restrict__ c,
                            unsigned short* __restrict__ da, unsigned short* __restrict__ db,
                            unsigned short* __restrict__ dc) {
  const int NA = (MM * EE) / 4, NBq = (K3 * EE) / 4, NC = (EE * EE) / 4;
  const int total = NA + NBq + NC;
  for (int i = blockIdx.x * blockDim.x + threadIdx.x; i < total; i += gridDim.x * blockDim.x) {
    const float* s; unsigned short* d; int j;
    if (i < NA)            { s = a; d = da; j = i; }
    else if (i < NA + NBq) { s = b; d = db; j = i - NA; }
    else                   { s = c; d = dc; j = i - NA - NBq; }
    f32x4 v = ((const f32x4*)s)[j];
    u16x4 o;
    o[0] = f2bf(v[0]); o[1] = f2bf(v[1]); o[2] = f2bf(v[2]); o[3] = f2bf(v[3]);
    ((u16x4*)d)[j] = o;
  }
}

// ---------------- GEMM: C[m][c] = sum_k A[m][k]*B[c][k] + bias[c] ----------------
// BM=128, BN=256, BK=32; 4 waves; 32 MFMA/wave/K-step (acc 4x8). Double-buffered
// LDS staging (48 KB), single barrier per K-step, stage issued right after it.
// MODE 0: fp32 out C[m][1024].  MODE 1 (NN=3072): bf16 out via padded-LDS
// coalesced epilogue, routed per column region:
//   c in [0,1024)    -> qo[m][c] * 0.125 (exact)
//   c in [1024,2048) -> kto[n][h][l][d]
//   c in [2048,3072) -> vo[m][c-2048]
template<int MODE>
__global__ __launch_bounds__(256, 2) void gemm_bt(
    const unsigned short* __restrict__ A, const unsigned short* __restrict__ B,
    const float* __restrict__ bias, float* __restrict__ Cf,
    unsigned short* __restrict__ qo, unsigned short* __restrict__ kto,
    unsigned short* __restrict__ vo)
{
  constexpr int NNc = (MODE == 1) ? 3072 : 1024;
  constexpr int BPC = NNc / 256;             // bcol tiles (12 or 4)
  constexpr int KD  = 1024;
  // staging: 2 bufs x (A 128x32 + B 256x32) = 24576 shorts (48 KB)
  // MODE1 epilogue bounce: 128 x 260 = 33280 shorts (66.6 KB), unioned
  constexpr int SMEM = (MODE == 1) ? 33280 : 24576;
  __shared__ __align__(16) unsigned short smem[SMEM];

  const int bid = blockIdx.x;
  const int q8 = gridDim.x >> 3;
  const int wgid = (bid & 7) * q8 + (bid >> 3);   // XCD-chunked bijective
  const int brow = wgid / BPC;                    // 8-brow slice per XCD
  const int bcol = wgid % BPC;

  const int tid = threadIdx.x;
  const int w = tid >> 6, lane = tid & 63;
  const int wr = w >> 1, wc = w & 1;
  const int lrow = lane & 15, g = lane >> 4;

  f32x4 acc[4][8];
#pragma unroll
  for (int i = 0; i < 4; ++i)
#pragma unroll
    for (int j = 0; j < 8; ++j) acc[i][j] = (f32x4){0.f, 0.f, 0.f, 0.f};

  const int r_in = lane >> 2;
  const int u = lane & 3;

  auto stage = [&](int kt) {
    unsigned short* base = smem + ((kt & 1) ? 12288 : 0);
    unsigned short* a_lds = base;            // [128][32]
    unsigned short* b_lds = base + 4096;     // [256][32]
    const size_t kcol = (size_t)kt * 32 + u * 8;
    gload16(A + (size_t)(brow * 128 + 16 * w + r_in) * KD + kcol,       &a_lds[(16 * w) * 32]);
    gload16(A + (size_t)(brow * 128 + 16 * (w + 4) + r_in) * KD + kcol, &a_lds[(16 * (w + 4)) * 32]);
#pragma unroll
    for (int i = 0; i < 4; ++i)
      gload16(B + (size_t)(bcol * 256 + 16 * (w + 4 * i) + r_in) * KD + kcol,
              &b_lds[(16 * (w + 4 * i)) * 32]);
  };

  const int KT = KD >> 5;
  stage(0);
  for (int kt = 0; kt < KT; ++kt) {
    __syncthreads();                         // buf[kt&1] staged; prev reads joined
    if (kt + 1 < KT) stage(kt + 1);          // early prefetch into buf^1
    const unsigned short* base = smem + ((kt & 1) ? 12288 : 0);
    const unsigned short* a_lds = base;
    const unsigned short* b_lds = base + 4096;
    bf16x8 af[4], bfr[8];
#pragma unroll
    for (int mt = 0; mt < 4; ++mt)
      af[mt] = *(const bf16x8*)&a_lds[(wr * 64 + mt * 16 + lrow) * 32 + g * 8];
#pragma unroll
    for (int nt = 0; nt < 8; ++nt)
      bfr[nt] = *(const bf16x8*)&b_lds[(wc * 128 + nt * 16 + lrow) * 32 + g * 8];
#pragma unroll
    for (int mt = 0; mt < 4; ++mt)
#pragma unroll
      for (int nt = 0; nt < 8; ++nt)
        acc[mt][nt] = mfma16(af[mt], bfr[nt], acc[mt][nt]);
  }

  if (MODE == 0) {
#pragma unroll
    for (int nt = 0; nt < 8; ++nt) {
      const int c = bcol * 256 + wc * 128 + nt * 16 + lrow;
      const float bv = bias[c];
#pragma unroll
      for (int mt = 0; mt < 4; ++mt) {
        const int m0 = brow * 128 + wr * 64 + mt * 16 + g * 4;
#pragma unroll
        for (int j = 0; j < 4; ++j)
          Cf[(size_t)(m0 + j) * NNc + c] = acc[mt][nt][j] + bv;
      }
    }
  } else {
    __syncthreads();                         // all tile reads done before reuse
    const float qs = (bcol < 4) ? 0.125f : 1.0f;   // uniform per block
    // padded bounce: row stride 260 shorts -> conflict-free scatter writes
#pragma unroll
    for (int nt = 0; nt < 8; ++nt) {
      const int c = bcol * 256 + wc * 128 + nt * 16 + lrow;
      const float bv = bias[c];
      const int lc = wc * 128 + nt * 16 + lrow;
#pragma unroll
      for (int mt = 0; mt < 4; ++mt) {
        const int lr0 = wr * 64 + mt * 16 + g * 4;
#pragma unroll
        for (int j = 0; j < 4; ++j)
          smem[(lr0 + j) * 260 + lc] = f2bf((acc[mt][nt][j] + bv) * qs);
      }
    }
    __syncthreads();
    // cooperative writer: 32 x 16B units per row -> 512B contiguous runs
#pragma unroll
    for (int i = 0; i < 16; ++i) {
      const int unit = i * 256 + tid;        // 0..4095
      const int r = unit >> 5, cu = unit & 31;
      const u16x8 val = *(const u16x8*)&smem[r * 260 + cu * 8];
      const int m = brow * 128 + r;
      const int c = bcol * 256 + cu * 8;
      const int region = c >> 10, cl = c & 1023;
      if (region == 0)      *(u16x8*)&qo[(size_t)m * EE + cl] = val;
      else if (region == 2) *(u16x8*)&vo[(size_t)m * EE + cl] = val;
      else *(u16x8*)&kto[((size_t)((m & 7) * HH + (cl >> 6)) * LL + (m >> 3)) * DD + (cl & 63)] = val;
    }
  }
}

// ---------------- V transpose: v[m][1024] -> vt[n][h][d][s] ----------------
__global__ void transpose_v(const unsigned short* __restrict__ v, unsigned short* __restrict__ vt) {
  __shared__ __align__(16) unsigned short tile[64][68];
  const int b = blockIdx.x;                 // 2048
  const int lchunk = b & 15, h = (b >> 4) & 15, n = b >> 8;
  const int t = threadIdx.x;
  const int c4 = (t & 15) * 4, r = t >> 4;
#pragma unroll
  for (int p = 0; p < 4; ++p) {
    const int l = lchunk * 64 + p * 16 + r;
    u16x4 x = *(const u16x4*)&v[(size_t)(l * NB + n) * EE + h * DD + c4];
    *(u16x4*)&tile[p * 16 + r][c4] = x;
  }
  __syncthreads();
#pragma unroll
  for (int p = 0; p < 4; ++p) {
    const int d = p * 16 + r;
    u16x4 o;
#pragma unroll
    for (int i = 0; i < 4; ++i) o[i] = tile[c4 + i][d];
    *(u16x4*)&vt[((size_t)(n * HH + h) * DD + d) * LL + lchunk * 64 + c4] = o;
  }
}

// ---------------- flash attention (single pass, unnormalized accum) ----------------
// grid 512 = n(8, XCD) x h(16) x ltile(4 of 256 rows); block 256 = 4 waves.
// Each wave owns FOUR 16-row q-tiles: 4 independent QK->exp->PV chains hide
// latency; K ds_reads and V fragment loads amortized over 4 tiles. K chunk
// staged to LDS (XOR-swizzled source), double-buffered, 1 barrier/chunk.
__global__ __launch_bounds__(256) void attn_flash(
    const unsigned short* __restrict__ q,    // [m][1024] bf16, pre-scaled by 0.125
    const unsigned short* __restrict__ kt,   // [n][h][s][64]
    const unsigned short* __restrict__ vt,   // [n][h][64][1024]
    unsigned short* __restrict__ ctxo,       // [m][1024] bf16
    float* __restrict__ rinvb)               // [n][h][1024]
{
  __shared__ __align__(16) unsigned short kc[2][64][64];      // 16 KB, swizzled
  __shared__ __align__(16) unsigned short pl[4][4][16][72];   // 36.9 KB [wave][tile][l][s]

  const int bid = blockIdx.x;
  const int n = bid & 7;
  const int rest = bid >> 3;        // 0..63
  const int h = rest >> 2;          // 0..15
  const int lt = (rest & 3) << 8;   // 0, 256, 512, 768
  const int tid = threadIdx.x;
  const int wv = tid >> 6, lane = tid & 63;
  const int ll = lane & 15, g = lane >> 4;
  const int a3 = ll & 7;

  // q fragments for 4 tiles
  bf16x8 qf0[4], qf1[4];
#pragma unroll
  for (int T = 0; T < 4; ++T) {
    const int lr = lt + T * 64 + wv * 16 + ll;
    const unsigned short* qp = q + ((size_t)lr * NB + n) * EE + h * DD + g * 8;
    qf0[T] = *(const bf16x8*)qp;
    qf1[T] = *(const bf16x8*)(qp + 32);
  }

  const unsigned short* kslab = kt + (size_t)(n * HH + h) * LL * DD;
  const unsigned short* vbase = vt + (size_t)(n * HH + h) * DD * LL;

  // staging: lane lam -> LDS row lam/8, unit lam%8; source unit (lam%8)^(row&7)
  const int r8 = lane >> 3;
  const int c16 = (lane & 7) ^ r8;
  // swizzled read offsets (bytes; 128B rows): row&7 == ll&7 == a3
  const int kof0 = ll * 128 + ((g ^ a3) << 4);        // k units 0..3
  const int kof1 = ll * 128 + (((4 + g) ^ a3) << 4);  // k units 4..7

  auto stageK = [&](int buf, int ch) {
    unsigned short* kd = &kc[buf][wv * 16][0];
    const unsigned short* src = kslab + (size_t)(ch * 64 + wv * 16) * DD;
    gload16(src + (size_t)r8 * DD + c16 * 8,       kd);
    gload16(src + (size_t)(8 + r8) * DD + c16 * 8, kd + 8 * 64);
  };

  f32x4 ctx[4][4];    // [tile][dt] — static indices after full unroll
  f32x4 sum[4];
#pragma unroll
  for (int T = 0; T < 4; ++T) {
    sum[T] = (f32x4){0.f, 0.f, 0.f, 0.f};
#pragma unroll
    for (int dt = 0; dt < 4; ++dt) ctx[T][dt] = (f32x4){0.f, 0.f, 0.f, 0.f};
  }

  char* plb = (char*)&pl[wv][0][0][0];      // tile stride 2304 B, row stride 144 B

  stageK(0, 0);
  for (int ch = 0; ch < 16; ++ch) {
    __syncthreads();                 // buf[ch&1] staged; prev iter's reads joined
    const int buf = ch & 1;
    const char* kb = (const char*)&kc[buf][0][0];

    // V loads first (consumed at PV -> their waitcnt won't drain the stage)
    bf16x8 vf0[4], vf1[4];
#pragma unroll
    for (int dt = 0; dt < 4; ++dt) {
      const unsigned short* vp = vbase + (size_t)(dt * 16 + ll) * LL + ch * 64 + g * 8;
      vf0[dt] = *(const bf16x8*)vp;
      vf1[dt] = *(const bf16x8*)(vp + 32);
    }
    if (ch < 15) stageK(buf ^ 1, ch + 1);   // early prefetch, covered by chunk body

    // QK^T + exp + stage P, 4 tiles per K fragment
#pragma unroll
    for (int t = 0; t < 4; ++t) {
      const bf16x8 kf0 = *(const bf16x8*)(kb + t * 2048 + kof0);
      const bf16x8 kf1 = *(const bf16x8*)(kb + t * 2048 + kof1);
#pragma unroll
      for (int T = 0; T < 4; ++T) {
        f32x4 sc = (f32x4){0.f, 0.f, 0.f, 0.f};
        sc = mfma16(kf0, qf0[T], sc);
        sc = mfma16(kf1, qf1[T], sc);
        f32x4 p;
#pragma unroll
        for (int j = 0; j < 4; ++j) p[j] = __expf(sc[j]);
        sum[T] += p;
        uint2 wT; wT.x = cvtpk(p[0], p[1]); wT.y = cvtpk(p[2], p[3]);
        *(uint2*)(plb + T * 2304 + ll * 144 + (t * 16 + g * 4) * 2) = wT;
      }
    }
    // PV per tile (pf transient, caps register pressure)
#pragma unroll
    for (int T = 0; T < 4; ++T) {
      const bf16x8 pf0 = *(const bf16x8*)(plb + T * 2304 + ll * 144 + g * 16);
      const bf16x8 pf1 = *(const bf16x8*)(plb + T * 2304 + ll * 144 + 64 + g * 16);
#pragma unroll
      for (int dt = 0; dt < 4; ++dt) {
        ctx[T][dt] = mfma16(vf0[dt], pf0, ctx[T][dt]);
        ctx[T][dt] = mfma16(vf1[dt], pf1, ctx[T][dt]);
      }
    }
  }

  // per-tile row sums -> rinv, normalize, store
#pragma unroll
  for (int T = 0; T < 4; ++T) {
    float s1 = sum[T][0] + sum[T][1] + sum[T][2] + sum[T][3];
    s1 += __shfl_xor(s1, 16); s1 += __shfl_xor(s1, 32);
    const float rinv = 1.0f / s1;
    if (lane < 16) rinvb[(size_t)(n * HH + h) * LL + lt + T * 64 + wv * 16 + lane] = rinv;
    const int lr = lt + T * 64 + wv * 16 + ll;
    unsigned short* cp = ctxo + ((size_t)lr * NB + n) * EE + h * DD;
#pragma unroll
    for (int dt = 0; dt < 4; ++dt) {
      uint2 o;
      o.x = cvtpk(ctx[T][dt][0] * rinv, ctx[T][dt][1] * rinv);
      o.y = cvtpk(ctx[T][dt][2] * rinv, ctx[T][dt][3] * rinv);
      *(uint2*)(cp + dt * 16 + g * 4) = o;
    }
  }
}

// ---------------- head-mean attention output (recompute QK with known rinv) ----------------
// grid 1024 = n(8, XCD) x [sh(8 of 128 s) x lt(16 of 64 rows)]; block 256 = 4 waves.
// Next-head K stage issued right after the barrier (after q loads).
__global__ __launch_bounds__(256) void attn_mean(
    const unsigned short* __restrict__ q,    // [m][1024] bf16, pre-scaled by 0.125
    const unsigned short* __restrict__ kt,   // [n][h][s][64]
    const float* __restrict__ rinvb,         // [n][h][1024]
    float* __restrict__ attn_out)            // [n][1024][1024]
{
  __shared__ __align__(16) unsigned short kc[2][128][64];  // 32KB, swizzled

  const int bid = blockIdx.x;
  const int n = bid & 7;
  const int r = bid >> 3;                    // 0..127
  const int sh = r & 7;
  const int lt = (r >> 3) << 6;
  const int tid = threadIdx.x;
  const int wv = tid >> 6, lane = tid & 63;
  const int ll = lane & 15, g = lane >> 4;
  const int a3 = ll & 7;
  const int sb = sh << 7;
  const int lrow = lt + wv * 16 + ll;

  const int r8 = lane >> 3;
  const int c16 = (lane & 7) ^ r8;
  const int kof0 = ll * 128 + ((g ^ a3) << 4);
  const int kof1 = ll * 128 + (((4 + g) ^ a3) << 4);

  const unsigned short* kwin = kt + (size_t)n * HH * LL * DD + (size_t)sb * DD;

  auto stage = [&](int buf, int h) {
    unsigned short* kd = &kc[buf][wv * 32][0];
    const unsigned short* src = kwin + (size_t)h * LL * DD + (size_t)(wv * 32) * DD;
#pragma unroll
    for (int i = 0; i < 4; ++i)
      gload16(src + (size_t)(i * 8 + r8) * DD + c16 * 8, kd + i * 8 * 64);
  };

  float rv[16];
#pragma unroll
  for (int h = 0; h < HH; ++h) rv[h] = rinvb[(size_t)(n * HH + h) * LL + lrow];

  const unsigned short* qb2 = q + ((size_t)lrow * NB + n) * EE + g * 8;

  f32x4 acc[8];
#pragma unroll
  for (int i = 0; i < 8; ++i) acc[i] = (f32x4){0.f, 0.f, 0.f, 0.f};

  stage(0, 0);
  for (int h = 0; h < HH; ++h) {
    __syncthreads();                 // buf[h&1] staged; prev reads joined
    const char* kb = (const char*)&kc[h & 1][0][0];
    const unsigned short* qp = qb2 + h * DD;
    const bf16x8 qf0 = *(const bf16x8*)qp;   // q loads first (consumed this iter)
    const bf16x8 qf1 = *(const bf16x8*)(qp + 32);
    if (h + 1 < HH) stage((h + 1) & 1, h + 1);   // early prefetch
    const float rvh = rv[h];
#pragma unroll
    for (int t = 0; t < 8; ++t) {
      bf16x8 kf0 = *(const bf16x8*)(kb + t * 2048 + kof0);
      bf16x8 kf1 = *(const bf16x8*)(kb + t * 2048 + kof1);
      f32x4 sc = (f32x4){0.f, 0.f, 0.f, 0.f};
      sc = mfma16(kf0, qf0, sc);
      sc = mfma16(kf1, qf1, sc);
#pragma unroll
      for (int j = 0; j < 4; ++j) acc[t][j] += __expf(sc[j]) * rvh;
    }
  }

  float* ap = attn_out + ((size_t)n * LL + lrow) * LL + sb + g * 4;
#pragma unroll
  for (int t = 0; t < 8; ++t) *(f32x4*)(ap + t * 16) = acc[t] * 0.0625f;
}

extern "C" void kernel_launch(void* const* d_in, const int* in_sizes, int n_in,
                              void* d_out, int out_size, void* d_ws, size_t ws_size,
                              hipStream_t stream) {
  const float* x   = (const float*)d_in[0];
  const float* win = (const float*)d_in[1];
  const float* bin = (const float*)d_in[2];
  const float* ow  = (const float*)d_in[3];
  const float* ob  = (const float*)d_in[4];
  float* out = (float*)d_out;

  const size_t need = ((size_t)MM * EE * 5 + (size_t)K3 * EE + (size_t)EE * EE) * 2
                    + (size_t)NB * HH * LL * 4;
  if (ws_size < need) return;

  unsigned short* ws  = (unsigned short*)d_ws;
  unsigned short* xb  = ws;                        // [8192][1024]  (reused as ctx)
  unsigned short* wb  = xb + (size_t)MM * EE;      // [3072][1024]
  unsigned short* owb = wb + (size_t)K3 * EE;      // [1024][1024]
  unsigned short* qb  = owb + (size_t)EE * EE;     // [8192][1024]
  unsigned short* ktb = qb + (size_t)MM * EE;      // [8][16][1024][64]
  unsigned short* vb  = ktb + (size_t)MM * EE;     // [8192][1024]
  unsigned short* vtb = vb + (size_t)MM * EE;      // [8][16][64][1024]
  float* rinvb = (float*)(vtb + (size_t)MM * EE);  // [8][16][1024]
  unsigned short* ctx = xb;

  cvt3_kernel<<<2048, 256, 0, stream>>>(x, win, ow, xb, wb, owb);
  gemm_bt<1><<<64 * (K3 / 256), 256, 0, stream>>>(xb, wb, bin, nullptr, qb, ktb, vb);
  transpose_v<<<2048, 256, 0, stream>>>(vb, vtb);
  attn_flash<<<512, 256, 0, stream>>>(qb, ktb, vtb, ctx, rinvb);
  attn_mean<<<1024, 256, 0, stream>>>(qb, ktb, rinvb, out + (size_t)MM * EE);
  gemm_bt<0><<<64 * (EE / 256), 256, 0, stream>>>(ctx, owb, ob, out, nullptr, nullptr, nullptr);
}

// Round 12
// 201.936 us; speedup vs baseline: 1.3729x; 1.0080x over previous
//
#include <hip/hip_runtime.h>
#include <stdint.h>

#define LL 1024
#define NB 8
#define EE 1024
#define HH 16
#define DD 64
#define MM (LL*NB)      // 8192 rows (l*NB+n)
#define K3 (3*EE)       // 3072

typedef __attribute__((ext_vector_type(8))) short bf16x8;   // 8 bf16 in 4 VGPRs
typedef __attribute__((ext_vector_type(4))) float f32x4;
typedef __attribute__((ext_vector_type(4))) unsigned short u16x4;
typedef __attribute__((ext_vector_type(8))) unsigned short u16x8;

__device__ __forceinline__ unsigned short f2bf(float f) {
  uint32_t u = __builtin_bit_cast(uint32_t, f);
  u += 0x7fffu + ((u >> 16) & 1u);           // RNE
  return (unsigned short)(u >> 16);
}
// HW RNE pack: dst = [bf16(hi)|bf16(lo)] — bit-identical to f2bf pairs
__device__ __forceinline__ uint32_t cvtpk(float lo, float hi) {
  uint32_t d;
  asm volatile("v_cvt_pk_bf16_f32 %0, %1, %2" : "=v"(d) : "v"(lo), "v"(hi));
  return d;
}
__device__ __forceinline__ f32x4 mfma16(bf16x8 a, bf16x8 b, f32x4 c) {
  return __builtin_amdgcn_mfma_f32_16x16x32_bf16(a, b, c, 0, 0, 0);
}
__device__ __forceinline__ void gload16(const unsigned short* src, unsigned short* dst) {
  __builtin_amdgcn_global_load_lds(
      (const __attribute__((address_space(1))) uint32_t*)src,
      (__attribute__((address_space(3))) uint32_t*)dst, 16, 0, 0);
}

// ---------------- fp32 -> bf16 convert (all three inputs, one launch) ----------------
__global__ void cvt3_kernel(const float* __restrict__ a, const float* __restrict__ b,
                            const float* __restrict__ c,
                            unsigned short* __restrict__ da, unsigned short* __restrict__ db,
                            unsigned short* __restrict__ dc) {
  const int NA = (MM * EE) / 4, NBq = (K3 * EE) / 4, NC = (EE * EE) / 4;
  const int total = NA + NBq + NC;
  for (int i = blockIdx.x * blockDim.x + threadIdx.x; i < total; i += gridDim.x * blockDim.x) {
    const float* s; unsigned short* d; int j;
    if (i < NA)            { s = a; d = da; j = i; }
    else if (i < NA + NBq) { s = b; d = db; j = i - NA; }
    else                   { s = c; d = dc; j = i - NA - NBq; }
    f32x4 v = ((const f32x4*)s)[j];
    u16x4 o;
    o[0] = f2bf(v[0]); o[1] = f2bf(v[1]); o[2] = f2bf(v[2]); o[3] = f2bf(v[3]);
    ((u16x4*)d)[j] = o;
  }
}

// ======== in-proj GEMM: 256x256 tile, BK=64, 8 waves, counted-vmcnt schedule ========
// C[m][c] = sum_k A[m][k]*W[c][k] + bias[c], routed: c<1024 -> qo*0.125,
// 1024..2047 -> kto[n][h][l][d], 2048.. -> vo. 4 phases/K-tile x 16 MFMA;
// next tile's loads issued 2/phase; vmcnt(2) (never 0) + raw s_barrier at phase 0;
// one trailing barrier per K-tile (WAR protection for buffer reuse).
__global__ __launch_bounds__(512, 2) void gemm8p(
    const unsigned short* __restrict__ A, const unsigned short* __restrict__ B,
    const float* __restrict__ bias,
    unsigned short* __restrict__ qo, unsigned short* __restrict__ kto,
    unsigned short* __restrict__ vo)
{
  __shared__ __align__(16) unsigned short smem[65536];   // 128 KB: 2 x (A 32K + B 32K shorts)

  const int bid = blockIdx.x;                 // 384 = 32 brow x 12 bcol
  const int wgid = (bid & 7) * 48 + (bid >> 3);   // XCD-chunked bijective
  const int brow = wgid / 12;
  const int bcol = wgid % 12;

  const int tid = threadIdx.x;
  const int w = tid >> 6, lane = tid & 63;
  const int wm = w >> 2, wn = w & 3;          // wave grid 2(M) x 4(N)
  const int ll = lane & 15, g = lane >> 4;
  const int a3 = ll & 7;
  const int r8l = lane >> 3;                  // 0..7
  const int su = (lane & 7) ^ r8l;            // swizzled source 16B-unit

  // swizzled read offsets (bytes) within a [rows][64-short] tile, 128B rows
  const int kof0 = ll * 128 + ((g ^ a3) << 4);        // k 0..31
  const int kof1 = ll * 128 + (((4 + g) ^ a3) << 4);  // k 32..63

  // stage slot s of tile ktt: s<4 = A rows [64s,64s+64), s>=4 = B rows
  auto issue = [&](int ktt, int s) {
    const int nb = ktt & 1;
    const bool isA = (s < 4);
    const int i = isA ? s : s - 4;
    unsigned short* dst = smem + nb * 32768 + (isA ? 0 : 16384) + (64 * i + 8 * w) * 64;
    const unsigned short* src =
        (isA ? A + (size_t)(brow * 256 + 64 * i + 8 * w + r8l) * 1024
             : B + (size_t)(bcol * 256 + 64 * i + 8 * w + r8l) * 1024)
        + ktt * 64 + su * 8;
    gload16(src, dst);
  };

  f32x4 acc[8][4];
#pragma unroll
  for (int i = 0; i < 8; ++i)
#pragma unroll
    for (int j = 0; j < 4; ++j) acc[i][j] = (f32x4){0.f, 0.f, 0.f, 0.f};

  // prologue: tile 0 fully staged (8 outstanding loads)
#pragma unroll
  for (int s = 0; s < 8; ++s) issue(0, s);

  for (int kt = 0; kt < 16; ++kt) {
    const char* Ab = (const char*)(smem + (kt & 1) * 32768) + (wm * 128) * 128;
    const char* Bb = (const char*)(smem + (kt & 1) * 32768 + 16384) + (wn * 64) * 128;

    // ---- phase 0: issue 2, counted vmcnt, barrier, B-frags + q0 ----
    if (kt < 15) {
      issue(kt + 1, 0); issue(kt + 1, 1);
      asm volatile("s_waitcnt vmcnt(2)" ::: "memory");
    } else {
      asm volatile("s_waitcnt vmcnt(0)" ::: "memory");
    }
    __builtin_amdgcn_s_barrier();
    __builtin_amdgcn_sched_barrier(0);

    bf16x8 bf[4][2];
#pragma unroll
    for (int nt = 0; nt < 4; ++nt) {
      bf[nt][0] = *(const bf16x8*)(Bb + nt * 2048 + kof0);
      bf[nt][1] = *(const bf16x8*)(Bb + nt * 2048 + kof1);
    }
    {
      bf16x8 a0k0 = *(const bf16x8*)(Ab + 0 * 2048 + kof0);
      bf16x8 a0k1 = *(const bf16x8*)(Ab + 0 * 2048 + kof1);
      bf16x8 a1k0 = *(const bf16x8*)(Ab + 1 * 2048 + kof0);
      bf16x8 a1k1 = *(const bf16x8*)(Ab + 1 * 2048 + kof1);
      __builtin_amdgcn_s_setprio(1);
#pragma unroll
      for (int nt = 0; nt < 4; ++nt) {
        acc[0][nt] = mfma16(a0k0, bf[nt][0], acc[0][nt]);
        acc[0][nt] = mfma16(a0k1, bf[nt][1], acc[0][nt]);
        acc[1][nt] = mfma16(a1k0, bf[nt][0], acc[1][nt]);
        acc[1][nt] = mfma16(a1k1, bf[nt][1], acc[1][nt]);
      }
      __builtin_amdgcn_s_setprio(0);
    }
    // ---- phase 1 ----
    if (kt < 15) { issue(kt + 1, 2); issue(kt + 1, 3); }
    {
      bf16x8 a0k0 = *(const bf16x8*)(Ab + 2 * 2048 + kof0);
      bf16x8 a0k1 = *(const bf16x8*)(Ab + 2 * 2048 + kof1);
      bf16x8 a1k0 = *(const bf16x8*)(Ab + 3 * 2048 + kof0);
      bf16x8 a1k1 = *(const bf16x8*)(Ab + 3 * 2048 + kof1);
      __builtin_amdgcn_s_setprio(1);
#pragma unroll
      for (int nt = 0; nt < 4; ++nt) {
        acc[2][nt] = mfma16(a0k0, bf[nt][0], acc[2][nt]);
        acc[2][nt] = mfma16(a0k1, bf[nt][1], acc[2][nt]);
        acc[3][nt] = mfma16(a1k0, bf[nt][0], acc[3][nt]);
        acc[3][nt] = mfma16(a1k1, bf[nt][1], acc[3][nt]);
      }
      __builtin_amdgcn_s_setprio(0);
    }
    // ---- phase 2 ----
    if (kt < 15) { issue(kt + 1, 4); issue(kt + 1, 5); }
    {
      bf16x8 a0k0 = *(const bf16x8*)(Ab + 4 * 2048 + kof0);
      bf16x8 a0k1 = *(const bf16x8*)(Ab + 4 * 2048 + kof1);
      bf16x8 a1k0 = *(const bf16x8*)(Ab + 5 * 2048 + kof0);
      bf16x8 a1k1 = *(const bf16x8*)(Ab + 5 * 2048 + kof1);
      __builtin_amdgcn_s_setprio(1);
#pragma unroll
      for (int nt = 0; nt < 4; ++nt) {
        acc[4][nt] = mfma16(a0k0, bf[nt][0], acc[4][nt]);
        acc[4][nt] = mfma16(a0k1, bf[nt][1], acc[4][nt]);
        acc[5][nt] = mfma16(a1k0, bf[nt][0], acc[5][nt]);
        acc[5][nt] = mfma16(a1k1, bf[nt][1], acc[5][nt]);
      }
      __builtin_amdgcn_s_setprio(0);
    }
    // ---- phase 3 + trailing barrier ----
    if (kt < 15) { issue(kt + 1, 6); issue(kt + 1, 7); }
    {
      bf16x8 a0k0 = *(const bf16x8*)(Ab + 6 * 2048 + kof0);
      bf16x8 a0k1 = *(const bf16x8*)(Ab + 6 * 2048 + kof1);
      bf16x8 a1k0 = *(const bf16x8*)(Ab + 7 * 2048 + kof0);
      bf16x8 a1k1 = *(const bf16x8*)(Ab + 7 * 2048 + kof1);
      __builtin_amdgcn_s_setprio(1);
#pragma unroll
      for (int nt = 0; nt < 4; ++nt) {
        acc[6][nt] = mfma16(a0k0, bf[nt][0], acc[6][nt]);
        acc[6][nt] = mfma16(a0k1, bf[nt][1], acc[6][nt]);
        acc[7][nt] = mfma16(a1k0, bf[nt][0], acc[7][nt]);
        acc[7][nt] = mfma16(a1k1, bf[nt][1], acc[7][nt]);
      }
      __builtin_amdgcn_s_setprio(0);
    }
    __builtin_amdgcn_sched_barrier(0);
    __builtin_amdgcn_s_barrier();            // all reads of buf[kt] done
  }

  // ---- epilogue: two half-passes through padded LDS bounce (128 x 260) ----
  const int region = bcol >> 2;              // 0:q 1:k^T 2:v  (block-uniform)
  const float qs = (region == 0) ? 0.125f : 1.0f;
#pragma unroll
  for (int half = 0; half < 2; ++half) {
    if (wm == half) {
#pragma unroll
      for (int nt = 0; nt < 4; ++nt) {
        const int c = bcol * 256 + wn * 64 + nt * 16 + ll;
        const float bv = bias[c];
        const int lc = wn * 64 + nt * 16 + ll;
#pragma unroll
        for (int mt = 0; mt < 8; ++mt) {
          const int lr0 = mt * 16 + g * 4;
#pragma unroll
          for (int j = 0; j < 4; ++j)
            smem[(lr0 + j) * 260 + lc] = f2bf((acc[mt][nt][j] + bv) * qs);
        }
      }
    }
    __syncthreads();
#pragma unroll
    for (int it = 0; it < 8; ++it) {
      const int unit = it * 512 + tid;       // 0..4095 = 128 rows x 32 units
      const int r = unit >> 5, cu = unit & 31;
      const u16x8 val = *(const u16x8*)&smem[r * 260 + cu * 8];
      const int m = brow * 256 + half * 128 + r;
      const int cl = (bcol & 3) * 256 + cu * 8;
      if (region == 0)      *(u16x8*)&qo[(size_t)m * EE + cl] = val;
      else if (region == 2) *(u16x8*)&vo[(size_t)m * EE + cl] = val;
      else *(u16x8*)&kto[((size_t)((m & 7) * HH + (cl >> 6)) * LL + (m >> 3)) * DD + (cl & 63)] = val;
    }
    __syncthreads();
  }
}

// ---------------- out-proj GEMM (round-11 proven): BM=128, BN=256, fp32 out ----------------
__global__ __launch_bounds__(256, 2) void gemm_out(
    const unsigned short* __restrict__ A, const unsigned short* __restrict__ B,
    const float* __restrict__ bias, float* __restrict__ Cf)
{
  constexpr int KD = 1024;
  __shared__ __align__(16) unsigned short smem[24576];   // 48 KB: 2 x (A 4K + B 8K shorts)

  const int bid = blockIdx.x;
  const int q8 = gridDim.x >> 3;
  const int wgid = (bid & 7) * q8 + (bid >> 3);
  const int brow = wgid >> 2;                 // 64 brow x 4 bcol
  const int bcol = wgid & 3;

  const int tid = threadIdx.x;
  const int w = tid >> 6, lane = tid & 63;
  const int wr = w >> 1, wc = w & 1;
  const int lrow = lane & 15, g = lane >> 4;

  f32x4 acc[4][8];
#pragma unroll
  for (int i = 0; i < 4; ++i)
#pragma unroll
    for (int j = 0; j < 8; ++j) acc[i][j] = (f32x4){0.f, 0.f, 0.f, 0.f};

  const int r_in = lane >> 2;
  const int u = lane & 3;

  auto stage = [&](int kt) {
    unsigned short* base = smem + ((kt & 1) ? 12288 : 0);
    unsigned short* a_lds = base;
    unsigned short* b_lds = base + 4096;
    const size_t kcol = (size_t)kt * 32 + u * 8;
    gload16(A + (size_t)(brow * 128 + 16 * w + r_in) * KD + kcol,       &a_lds[(16 * w) * 32]);
    gload16(A + (size_t)(brow * 128 + 16 * (w + 4) + r_in) * KD + kcol, &a_lds[(16 * (w + 4)) * 32]);
#pragma unroll
    for (int i = 0; i < 4; ++i)
      gload16(B + (size_t)(bcol * 256 + 16 * (w + 4 * i) + r_in) * KD + kcol,
              &b_lds[(16 * (w + 4 * i)) * 32]);
  };

  const int KT = KD >> 5;
  stage(0);
  for (int kt = 0; kt < KT; ++kt) {
    __syncthreads();
    if (kt + 1 < KT) stage(kt + 1);
    const unsigned short* base = smem + ((kt & 1) ? 12288 : 0);
    const unsigned short* a_lds = base;
    const unsigned short* b_lds = base + 4096;
    bf16x8 af[4], bfr[8];
#pragma unroll
    for (int mt = 0; mt < 4; ++mt)
      af[mt] = *(const bf16x8*)&a_lds[(wr * 64 + mt * 16 + lrow) * 32 + g * 8];
#pragma unroll
    for (int nt = 0; nt < 8; ++nt)
      bfr[nt] = *(const bf16x8*)&b_lds[(wc * 128 + nt * 16 + lrow) * 32 + g * 8];
#pragma unroll
    for (int mt = 0; mt < 4; ++mt)
#pragma unroll
      for (int nt = 0; nt < 8; ++nt)
        acc[mt][nt] = mfma16(af[mt], bfr[nt], acc[mt][nt]);
  }

#pragma unroll
  for (int nt = 0; nt < 8; ++nt) {
    const int c = bcol * 256 + wc * 128 + nt * 16 + lrow;
    const float bv = bias[c];
#pragma unroll
    for (int mt = 0; mt < 4; ++mt) {
      const int m0 = brow * 128 + wr * 64 + mt * 16 + g * 4;
#pragma unroll
      for (int j = 0; j < 4; ++j)
        Cf[(size_t)(m0 + j) * 1024 + c] = acc[mt][nt][j] + bv;
    }
  }
}

// ---------------- V transpose: v[m][1024] -> vt[n][h][d][s] ----------------
__global__ void transpose_v(const unsigned short* __restrict__ v, unsigned short* __restrict__ vt) {
  __shared__ __align__(16) unsigned short tile[64][68];
  const int b = blockIdx.x;                 // 2048
  const int lchunk = b & 15, h = (b >> 4) & 15, n = b >> 8;
  const int t = threadIdx.x;
  const int c4 = (t & 15) * 4, r = t >> 4;
#pragma unroll
  for (int p = 0; p < 4; ++p) {
    const int l = lchunk * 64 + p * 16 + r;
    u16x4 x = *(const u16x4*)&v[(size_t)(l * NB + n) * EE + h * DD + c4];
    *(u16x4*)&tile[p * 16 + r][c4] = x;
  }
  __syncthreads();
#pragma unroll
  for (int p = 0; p < 4; ++p) {
    const int d = p * 16 + r;
    u16x4 o;
#pragma unroll
    for (int i = 0; i < 4; ++i) o[i] = tile[c4 + i][d];
    *(u16x4*)&vt[((size_t)(n * HH + h) * DD + d) * LL + lchunk * 64 + c4] = o;
  }
}

// ---------------- flash attention (single pass, unnormalized accum) ----------------
// grid 512 = n(8, XCD) x h(16) x ltile(4 of 256 rows); block 256 = 4 waves.
__global__ __launch_bounds__(256) void attn_flash(
    const unsigned short* __restrict__ q,    // [m][1024] bf16, pre-scaled by 0.125
    const unsigned short* __restrict__ kt,   // [n][h][s][64]
    const unsigned short* __restrict__ vt,   // [n][h][64][1024]
    unsigned short* __restrict__ ctxo,       // [m][1024] bf16
    float* __restrict__ rinvb)               // [n][h][1024]
{
  __shared__ __align__(16) unsigned short kc[2][64][64];      // 16 KB, swizzled
  __shared__ __align__(16) unsigned short pl[4][4][16][72];   // 36.9 KB [wave][tile][l][s]

  const int bid = blockIdx.x;
  const int n = bid & 7;
  const int rest = bid >> 3;        // 0..63
  const int h = rest >> 2;          // 0..15
  const int lt = (rest & 3) << 8;   // 0, 256, 512, 768
  const int tid = threadIdx.x;
  const int wv = tid >> 6, lane = tid & 63;
  const int ll = lane & 15, g = lane >> 4;
  const int a3 = ll & 7;

  bf16x8 qf0[4], qf1[4];
#pragma unroll
  for (int T = 0; T < 4; ++T) {
    const int lr = lt + T * 64 + wv * 16 + ll;
    const unsigned short* qp = q + ((size_t)lr * NB + n) * EE + h * DD + g * 8;
    qf0[T] = *(const bf16x8*)qp;
    qf1[T] = *(const bf16x8*)(qp + 32);
  }

  const unsigned short* kslab = kt + (size_t)(n * HH + h) * LL * DD;
  const unsigned short* vbase = vt + (size_t)(n * HH + h) * DD * LL;

  const int r8 = lane >> 3;
  const int c16 = (lane & 7) ^ r8;
  const int kof0 = ll * 128 + ((g ^ a3) << 4);
  const int kof1 = ll * 128 + (((4 + g) ^ a3) << 4);

  auto stageK = [&](int buf, int ch) {
    unsigned short* kd = &kc[buf][wv * 16][0];
    const unsigned short* src = kslab + (size_t)(ch * 64 + wv * 16) * DD;
    gload16(src + (size_t)r8 * DD + c16 * 8,       kd);
    gload16(src + (size_t)(8 + r8) * DD + c16 * 8, kd + 8 * 64);
  };

  f32x4 ctx[4][4];
  f32x4 sum[4];
#pragma unroll
  for (int T = 0; T < 4; ++T) {
    sum[T] = (f32x4){0.f, 0.f, 0.f, 0.f};
#pragma unroll
    for (int dt = 0; dt < 4; ++dt) ctx[T][dt] = (f32x4){0.f, 0.f, 0.f, 0.f};
  }

  char* plb = (char*)&pl[wv][0][0][0];

  stageK(0, 0);
  for (int ch = 0; ch < 16; ++ch) {
    __syncthreads();
    const int buf = ch & 1;
    const char* kb = (const char*)&kc[buf][0][0];

    bf16x8 vf0[4], vf1[4];
#pragma unroll
    for (int dt = 0; dt < 4; ++dt) {
      const unsigned short* vp = vbase + (size_t)(dt * 16 + ll) * LL + ch * 64 + g * 8;
      vf0[dt] = *(const bf16x8*)vp;
      vf1[dt] = *(const bf16x8*)(vp + 32);
    }
    if (ch < 15) stageK(buf ^ 1, ch + 1);

#pragma unroll
    for (int t = 0; t < 4; ++t) {
      const bf16x8 kf0 = *(const bf16x8*)(kb + t * 2048 + kof0);
      const bf16x8 kf1 = *(const bf16x8*)(kb + t * 2048 + kof1);
#pragma unroll
      for (int T = 0; T < 4; ++T) {
        f32x4 sc = (f32x4){0.f, 0.f, 0.f, 0.f};
        sc = mfma16(kf0, qf0[T], sc);
        sc = mfma16(kf1, qf1[T], sc);
        f32x4 p;
#pragma unroll
        for (int j = 0; j < 4; ++j) p[j] = __expf(sc[j]);
        sum[T] += p;
        uint2 wT; wT.x = cvtpk(p[0], p[1]); wT.y = cvtpk(p[2], p[3]);
        *(uint2*)(plb + T * 2304 + ll * 144 + (t * 16 + g * 4) * 2) = wT;
      }
    }
#pragma unroll
    for (int T = 0; T < 4; ++T) {
      const bf16x8 pf0 = *(const bf16x8*)(plb + T * 2304 + ll * 144 + g * 16);
      const bf16x8 pf1 = *(const bf16x8*)(plb + T * 2304 + ll * 144 + 64 + g * 16);
#pragma unroll
      for (int dt = 0; dt < 4; ++dt) {
        ctx[T][dt] = mfma16(vf0[dt], pf0, ctx[T][dt]);
        ctx[T][dt] = mfma16(vf1[dt], pf1, ctx[T][dt]);
      }
    }
  }

#pragma unroll
  for (int T = 0; T < 4; ++T) {
    float s1 = sum[T][0] + sum[T][1] + sum[T][2] + sum[T][3];
    s1 += __shfl_xor(s1, 16); s1 += __shfl_xor(s1, 32);
    const float rinv = 1.0f / s1;
    if (lane < 16) rinvb[(size_t)(n * HH + h) * LL + lt + T * 64 + wv * 16 + lane] = rinv;
    const int lr = lt + T * 64 + wv * 16 + ll;
    unsigned short* cp = ctxo + ((size_t)lr * NB + n) * EE + h * DD;
#pragma unroll
    for (int dt = 0; dt < 4; ++dt) {
      uint2 o;
      o.x = cvtpk(ctx[T][dt][0] * rinv, ctx[T][dt][1] * rinv);
      o.y = cvtpk(ctx[T][dt][2] * rinv, ctx[T][dt][3] * rinv);
      *(uint2*)(cp + dt * 16 + g * 4) = o;
    }
  }
}

// ---------------- head-mean attention output (recompute QK with known rinv) ----------------
__global__ __launch_bounds__(256) void attn_mean(
    const unsigned short* __restrict__ q,    // [m][1024] bf16, pre-scaled by 0.125
    const unsigned short* __restrict__ kt,   // [n][h][s][64]
    const float* __restrict__ rinvb,         // [n][h][1024]
    float* __restrict__ attn_out)            // [n][1024][1024]
{
  __shared__ __align__(16) unsigned short kc[2][128][64];  // 32KB, swizzled

  const int bid = blockIdx.x;
  const int n = bid & 7;
  const int r = bid >> 3;
  const int sh = r & 7;
  const int lt = (r >> 3) << 6;
  const int tid = threadIdx.x;
  const int wv = tid >> 6, lane = tid & 63;
  const int ll = lane & 15, g = lane >> 4;
  const int a3 = ll & 7;
  const int sb = sh << 7;
  const int lrow = lt + wv * 16 + ll;

  const int r8 = lane >> 3;
  const int c16 = (lane & 7) ^ r8;
  const int kof0 = ll * 128 + ((g ^ a3) << 4);
  const int kof1 = ll * 128 + (((4 + g) ^ a3) << 4);

  const unsigned short* kwin = kt + (size_t)n * HH * LL * DD + (size_t)sb * DD;

  auto stage = [&](int buf, int h) {
    unsigned short* kd = &kc[buf][wv * 32][0];
    const unsigned short* src = kwin + (size_t)h * LL * DD + (size_t)(wv * 32) * DD;
#pragma unroll
    for (int i = 0; i < 4; ++i)
      gload16(src + (size_t)(i * 8 + r8) * DD + c16 * 8, kd + i * 8 * 64);
  };

  float rv[16];
#pragma unroll
  for (int h = 0; h < HH; ++h) rv[h] = rinvb[(size_t)(n * HH + h) * LL + lrow];

  const unsigned short* qb2 = q + ((size_t)lrow * NB + n) * EE + g * 8;

  f32x4 acc[8];
#pragma unroll
  for (int i = 0; i < 8; ++i) acc[i] = (f32x4){0.f, 0.f, 0.f, 0.f};

  stage(0, 0);
  for (int h = 0; h < HH; ++h) {
    __syncthreads();
    const char* kb = (const char*)&kc[h & 1][0][0];
    const unsigned short* qp = qb2 + h * DD;
    const bf16x8 qf0 = *(const bf16x8*)qp;
    const bf16x8 qf1 = *(const bf16x8*)(qp + 32);
    if (h + 1 < HH) stage((h + 1) & 1, h + 1);
    const float rvh = rv[h];
#pragma unroll
    for (int t = 0; t < 8; ++t) {
      bf16x8 kf0 = *(const bf16x8*)(kb + t * 2048 + kof0);
      bf16x8 kf1 = *(const bf16x8*)(kb + t * 2048 + kof1);
      f32x4 sc = (f32x4){0.f, 0.f, 0.f, 0.f};
      sc = mfma16(kf0, qf0, sc);
      sc = mfma16(kf1, qf1, sc);
#pragma unroll
      for (int j = 0; j < 4; ++j) acc[t][j] += __expf(sc[j]) * rvh;
    }
  }

  float* ap = attn_out + ((size_t)n * LL + lrow) * LL + sb + g * 4;
#pragma unroll
  for (int t = 0; t < 8; ++t) *(f32x4*)(ap + t * 16) = acc[t] * 0.0625f;
}

extern "C" void kernel_launch(void* const* d_in, const int* in_sizes, int n_in,
                              void* d_out, int out_size, void* d_ws, size_t ws_size,
                              hipStream_t stream) {
  const float* x   = (const float*)d_in[0];
  const float* win = (const float*)d_in[1];
  const float* bin = (const float*)d_in[2];
  const float* ow  = (const float*)d_in[3];
  const float* ob  = (const float*)d_in[4];
  float* out = (float*)d_out;

  const size_t need = ((size_t)MM * EE * 5 + (size_t)K3 * EE + (size_t)EE * EE) * 2
                    + (size_t)NB * HH * LL * 4;
  if (ws_size < need) return;

  unsigned short* ws  = (unsigned short*)d_ws;
  unsigned short* xb  = ws;                        // [8192][1024]  (reused as ctx)
  unsigned short* wb  = xb + (size_t)MM * EE;      // [3072][1024]
  unsigned short* owb = wb + (size_t)K3 * EE;      // [1024][1024]
  unsigned short* qb  = owb + (size_t)EE * EE;     // [8192][1024]
  unsigned short* ktb = qb + (size_t)MM * EE;      // [8][16][1024][64]
  unsigned short* vb  = ktb + (size_t)MM * EE;     // [8192][1024]
  unsigned short* vtb = vb + (size_t)MM * EE;      // [8][16][64][1024]
  float* rinvb = (float*)(vtb + (size_t)MM * EE);  // [8][16][1024]
  unsigned short* ctx = xb;

  cvt3_kernel<<<2048, 256, 0, stream>>>(x, win, ow, xb, wb, owb);
  gemm8p<<<384, 512, 0, stream>>>(xb, wb, bin, qb, ktb, vb);
  transpose_v<<<2048, 256, 0, stream>>>(vb, vtb);
  attn_flash<<<512, 256, 0, stream>>>(qb, ktb, vtb, ctx, rinvb);
  attn_mean<<<1024, 256, 0, stream>>>(qb, ktb, rinvb, out + (size_t)MM * EE);
  gemm_out<<<256, 256, 0, stream>>>(ctx, owb, ob, out);
}